// Round 2
// baseline (578.508 us; speedup 1.0000x reference)
//
#include <hip/hip_runtime.h>
#include <hip/hip_fp16.h>

typedef _Float16 f16;
typedef _Float16 f16x8 __attribute__((ext_vector_type(8)));
typedef float f32x4 __attribute__((ext_vector_type(4)));

#define MFMA(a,b,c) __builtin_amdgcn_mfma_f32_16x16x32_f16((a),(b),(c),0,0,0)

// B=16384, IN=512, HID=1024, OUT=512, E=16, K=4
// ws budget: w1fr 16MB + w2fr 16MB + routing ~2.6MB = ~34.6MB (was 114.5MB -> overflow)

// w1: [16][512][1024] -> fragment layout: frag fid=((e*64+n0)*16+kc), lane l, elem i
//   = w1[e][kc*32+(l>>4)*8+i][n0*16+(l&15)]
__global__ void k_cvt_w1(const float* __restrict__ w1, f16* __restrict__ w1fr) {
  int fid = blockIdx.x * 4 + (threadIdx.x >> 6);
  int l = threadIdx.x & 63;
  int e = fid >> 10, n0 = (fid >> 4) & 63, kc = fid & 15;
  int kbase = kc * 32 + (l >> 4) * 8;
  int col = n0 * 16 + (l & 15);
  const float* src = w1 + ((size_t)e * 512 + kbase) * 1024 + col;
  f16x8 o;
  #pragma unroll
  for (int i = 0; i < 8; i++) o[i] = (f16)src[(size_t)i * 1024];
  *(f16x8*)(w1fr + (size_t)fid * 512 + l * 8) = o;
}

// w2: [16][1024][512] -> frag fid=((e*32+n0)*32+kc)
__global__ void k_cvt_w2(const float* __restrict__ w2, f16* __restrict__ w2fr) {
  int fid = blockIdx.x * 4 + (threadIdx.x >> 6);
  int l = threadIdx.x & 63;
  int e = fid >> 10, n0 = (fid >> 5) & 31, kc = fid & 31;
  int kbase = kc * 32 + (l >> 4) * 8;
  int col = n0 * 16 + (l & 15);
  const float* src = w2 + ((size_t)e * 1024 + kbase) * 512 + col;
  f16x8 o;
  #pragma unroll
  for (int i = 0; i < 8; i++) o[i] = (f16)src[(size_t)i * 512];
  *(f16x8*)(w2fr + (size_t)fid * 512 + l * 8) = o;
}

// ---------------- gating ----------------
__global__ void k_gate(const float* __restrict__ x, const float* __restrict__ wg,
                       int* __restrict__ tk_idx, float* __restrict__ tk_gate) {
  int w = threadIdx.x >> 6, l = threadIdx.x & 63;
  int r = blockIdx.x * 4 + w;
  float p[16];
  #pragma unroll
  for (int e = 0; e < 16; e++) p[e] = 0.f;
  const float* xr = x + (size_t)r * 512;
  #pragma unroll
  for (int t = 0; t < 8; t++) {
    float xv = xr[t * 64 + l];
    const float* wrow = wg + (t * 64 + l) * 16;
    #pragma unroll
    for (int e = 0; e < 16; e++) p[e] += xv * wrow[e];
  }
  #pragma unroll
  for (int e = 0; e < 16; e++) {
    float v = p[e];
    #pragma unroll
    for (int m = 32; m >= 1; m >>= 1) v += __shfl_xor(v, m);
    p[e] = v;
  }
  unsigned chosen = 0;
  float bv[4]; int bi[4];
  #pragma unroll
  for (int j = 0; j < 4; j++) {
    float best = -3.4e38f; int be = 0;
    #pragma unroll
    for (int e = 0; e < 16; e++) {
      bool ok = !((chosen >> e) & 1u) && (p[e] > best);
      if (ok) { best = p[e]; be = e; }
    }
    chosen |= 1u << be; bv[j] = best; bi[j] = be;
  }
  float m0 = bv[0];
  float e0 = __expf(bv[0] - m0), e1 = __expf(bv[1] - m0),
        e2 = __expf(bv[2] - m0), e3 = __expf(bv[3] - m0);
  float s = e0 + e1 + e2 + e3;
  if (l == 0) {
    *(int4*)(tk_idx + (size_t)r * 4) = make_int4(bi[0], bi[1], bi[2], bi[3]);
    *(float4*)(tk_gate + (size_t)r * 4) = make_float4(e0 / s, e1 / s, e2 / s, e3 / s);
  }
}

// ---------------- routing (deterministic compaction) ----------------
__global__ void k_route_count(const int* __restrict__ tk_idx, int* __restrict__ partial) {
  int e = blockIdx.x >> 6, chunk = blockIdx.x & 63;
  int t = threadIdx.x;
  int row = chunk * 256 + t;
  int4 tk = ((const int4*)tk_idx)[row];
  bool match = (tk.x == e) || (tk.y == e) || (tk.z == e) || (tk.w == e);
  unsigned long long m = __ballot(match);
  __shared__ int wc[4];
  if ((t & 63) == 0) wc[t >> 6] = (int)__popcll(m);
  __syncthreads();
  if (t == 0) partial[e * 64 + chunk] = wc[0] + wc[1] + wc[2] + wc[3];
}

__global__ void k_route_scan(const int* __restrict__ partial, int* __restrict__ chunk_base,
                             int* __restrict__ count) {
  int l = threadIdx.x; // 64 threads
  for (int e = 0; e < 16; e++) {
    int v = partial[e * 64 + l];
    int orig = v;
    #pragma unroll
    for (int off = 1; off < 64; off <<= 1) {
      int u = __shfl_up(v, off);
      if (l >= off) v += u;
    }
    chunk_base[e * 64 + l] = v - orig;
    if (l == 63) count[e] = v;
  }
}

__global__ void k_route_scatter(const int* __restrict__ tk_idx, const float* __restrict__ tk_gate,
                                const int* __restrict__ chunk_base, int* __restrict__ rows_pk,
                                float* __restrict__ gates_l) {
  int e = blockIdx.x >> 6, chunk = blockIdx.x & 63;
  int t = threadIdx.x, w = t >> 6, l = t & 63;
  int row = chunk * 256 + t;
  int4 tk = ((const int4*)tk_idx)[row];
  int j = (tk.x == e) ? 0 : (tk.y == e) ? 1 : (tk.z == e) ? 2 : (tk.w == e) ? 3 : -1;
  bool match = (j >= 0);
  unsigned long long m = __ballot(match);
  __shared__ int wc[4];
  if (l == 0) wc[w] = (int)__popcll(m);
  __syncthreads();
  int wbase = 0;
  #pragma unroll
  for (int i = 0; i < 4; i++) if (i < w) wbase += wc[i];
  if (match) {
    int pos = (int)__popcll(m & ((1ULL << l) - 1ULL));
    int idx = e * 16384 + chunk_base[e * 64 + chunk] + wbase + pos;
    rows_pk[idx] = row | (j << 16);
    gates_l[idx] = tk_gate[(size_t)row * 4 + j];
  }
}

// ---------------- zero output ----------------
__global__ void k_zero(float4* __restrict__ y4) {
  y4[blockIdx.x * 256 + threadIdx.x] = make_float4(0.f, 0.f, 0.f, 0.f);
}

// ---------------- fused expert FFN (fp16 MFMA) ----------------
// grid: 16 experts * 512 rowblocks; block 256 (4 waves); 32 rows per block
__global__ __launch_bounds__(256, 2) void k_expert(
    const float* __restrict__ x, const f16* __restrict__ w1fr, const f16* __restrict__ w2fr,
    const float* __restrict__ b1, const float* __restrict__ b2,
    const int* __restrict__ count, const int* __restrict__ rows_pk,
    const float* __restrict__ gates_l, float* __restrict__ y)
{
  int e = blockIdx.x >> 9;
  int rb = blockIdx.x & 511;
  int cnt = count[e];
  int mstart = rb * 32;
  if (mstart >= cnt) return;
  int nvalid = cnt - mstart; if (nvalid > 32) nvalid = 32;

  __shared__ f16 h_lds[32 * 1024];   // 64KB, swizzled (byte ^= (row&7)<<4)
  __shared__ f16 a_lds[32 * 128];    // 8KB, swizzled
  __shared__ int rowarr[32];
  __shared__ float gatearr[32];
  __shared__ float red[2][4][32];

  int t = threadIdx.x, w = t >> 6, l = t & 63;
  int lq = l >> 4, lr = l & 15;

  if (t < 32) {
    int src = e * 16384 + mstart + ((t < nvalid) ? t : 0);
    rowarr[t] = rows_pk[src];
    gatearr[t] = gates_l[src];
  }
  __syncthreads();

  const f16x8* w1f8 = (const f16x8*)w1fr;
  const f16x8* w2f8 = (const f16x8*)w2fr;

  f32x4 acc[2][16];
  #pragma unroll
  for (int a = 0; a < 2; a++)
    #pragma unroll
    for (int b = 0; b < 16; b++)
      #pragma unroll
      for (int q = 0; q < 4; q++) acc[a][b][q] = 0.f;

  // ---- stage 1: h = relu(x @ w1 + b1), K=512 in 4 chunks of 128 ----
  #pragma unroll 1
  for (int kc = 0; kc < 4; kc++) {
    #pragma unroll
    for (int rep = 0; rep < 2; rep++) {
      int idx = t + rep * 256;
      int r = idx >> 4, seg = idx & 15;
      int xr = rowarr[r] & 0xFFFF;
      const float* sp = x + (size_t)xr * 512 + kc * 128 + seg * 8;
      float4 u0 = *(const float4*)sp;
      float4 u1 = *(const float4*)(sp + 4);
      f16x8 v;
      v[0] = (f16)u0.x; v[1] = (f16)u0.y; v[2] = (f16)u0.z; v[3] = (f16)u0.w;
      v[4] = (f16)u1.x; v[5] = (f16)u1.y; v[6] = (f16)u1.z; v[7] = (f16)u1.w;
      int byte = (r * 256 + seg * 16) ^ ((r & 7) << 4);
      *(f16x8*)((char*)a_lds + byte) = v;
    }
    __syncthreads();
    #pragma unroll
    for (int ks = 0; ks < 4; ks++) {
      int byte0 = (lr * 256 + ks * 64 + lq * 16) ^ ((lr & 7) << 4);
      f16x8 a0 = *(const f16x8*)((char*)a_lds + byte0);
      int row1 = 16 + lr;
      int byte1 = (row1 * 256 + ks * 64 + lq * 16) ^ ((row1 & 7) << 4);
      f16x8 a1 = *(const f16x8*)((char*)a_lds + byte1);
      int kcg = kc * 4 + ks;
      #pragma unroll
      for (int n0 = 0; n0 < 16; n0++) {
        int n0g = w * 16 + n0;
        f16x8 bf = w1f8[(size_t)(((e * 64 + n0g) * 16 + kcg)) * 64 + l];
        acc[0][n0] = MFMA(a0, bf, acc[0][n0]);
        acc[1][n0] = MFMA(a1, bf, acc[1][n0]);
      }
    }
    __syncthreads();
  }

  // epilogue: bias + relu -> h_lds (fp16, swizzled)
  #pragma unroll
  for (int n0 = 0; n0 < 16; n0++) {
    int col = (w * 16 + n0) * 16 + lr;
    float bv = b1[e * 1024 + col];
    #pragma unroll
    for (int m0 = 0; m0 < 2; m0++) {
      #pragma unroll
      for (int q = 0; q < 4; q++) {
        int row = m0 * 16 + lq * 4 + q;
        float hv = acc[m0][n0][q] + bv;
        hv = fmaxf(hv, 0.f);
        int byte = (row * 2048 + col * 2) ^ ((row & 7) << 4);
        *(f16*)((char*)h_lds + byte) = (f16)hv;
      }
    }
  }
  __syncthreads();

  // ---- stage 2: logits = h @ w2 + b2, K=1024 ----
  f32x4 acc2[2][8];
  #pragma unroll
  for (int a = 0; a < 2; a++)
    #pragma unroll
    for (int b = 0; b < 8; b++)
      #pragma unroll
      for (int q = 0; q < 4; q++) acc2[a][b][q] = 0.f;

  #pragma unroll 2
  for (int kc2 = 0; kc2 < 32; kc2++) {
    int byte0 = (lr * 2048 + kc2 * 64 + lq * 16) ^ ((lr & 7) << 4);
    f16x8 a0 = *(const f16x8*)((char*)h_lds + byte0);
    int row1 = 16 + lr;
    int byte1 = (row1 * 2048 + kc2 * 64 + lq * 16) ^ ((row1 & 7) << 4);
    f16x8 a1 = *(const f16x8*)((char*)h_lds + byte1);
    #pragma unroll
    for (int n0 = 0; n0 < 8; n0++) {
      int n0g = w * 8 + n0;
      f16x8 bf = w2f8[(size_t)(((e * 32 + n0g) * 32 + kc2)) * 64 + l];
      acc2[0][n0] = MFMA(a0, bf, acc2[0][n0]);
      acc2[1][n0] = MFMA(a1, bf, acc2[1][n0]);
    }
  }

  // bias
  #pragma unroll
  for (int n0 = 0; n0 < 8; n0++) {
    float bv = b2[e * 512 + (w * 8 + n0) * 16 + lr];
    #pragma unroll
    for (int m0 = 0; m0 < 2; m0++)
      #pragma unroll
      for (int q = 0; q < 4; q++) acc2[m0][n0][q] += bv;
  }

  // ---- softmax across full row (512 cols over 4 waves) ----
  float rmax[2][4];
  #pragma unroll
  for (int m0 = 0; m0 < 2; m0++)
    #pragma unroll
    for (int q = 0; q < 4; q++) {
      float v = acc2[m0][0][q];
      #pragma unroll
      for (int n0 = 1; n0 < 8; n0++) v = fmaxf(v, acc2[m0][n0][q]);
      #pragma unroll
      for (int m = 1; m < 16; m <<= 1) v = fmaxf(v, __shfl_xor(v, m));
      rmax[m0][q] = v;
    }
  if (lr == 0) {
    #pragma unroll
    for (int m0 = 0; m0 < 2; m0++)
      #pragma unroll
      for (int q = 0; q < 4; q++) red[0][w][m0 * 16 + lq * 4 + q] = rmax[m0][q];
  }
  __syncthreads();
  float gmax[2][4];
  #pragma unroll
  for (int m0 = 0; m0 < 2; m0++)
    #pragma unroll
    for (int q = 0; q < 4; q++) {
      int row = m0 * 16 + lq * 4 + q;
      gmax[m0][q] = fmaxf(fmaxf(red[0][0][row], red[0][1][row]),
                          fmaxf(red[0][2][row], red[0][3][row]));
    }
  float psum[2][4];
  #pragma unroll
  for (int m0 = 0; m0 < 2; m0++)
    #pragma unroll
    for (int q = 0; q < 4; q++) psum[m0][q] = 0.f;
  #pragma unroll
  for (int m0 = 0; m0 < 2; m0++)
    #pragma unroll
    for (int n0 = 0; n0 < 8; n0++)
      #pragma unroll
      for (int q = 0; q < 4; q++) {
        float p = __expf(acc2[m0][n0][q] - gmax[m0][q]);
        acc2[m0][n0][q] = p;
        psum[m0][q] += p;
      }
  #pragma unroll
  for (int m0 = 0; m0 < 2; m0++)
    #pragma unroll
    for (int q = 0; q < 4; q++) {
      float v = psum[m0][q];
      #pragma unroll
      for (int m = 1; m < 16; m <<= 1) v += __shfl_xor(v, m);
      psum[m0][q] = v;
    }
  if (lr == 0) {
    #pragma unroll
    for (int m0 = 0; m0 < 2; m0++)
      #pragma unroll
      for (int q = 0; q < 4; q++) red[1][w][m0 * 16 + lq * 4 + q] = psum[m0][q];
  }
  __syncthreads();

  // ---- gated atomic accumulate into y (each (row,slot) unique -> 4 adds/elem) ----
  #pragma unroll
  for (int m0 = 0; m0 < 2; m0++) {
    #pragma unroll
    for (int q = 0; q < 4; q++) {
      int row = m0 * 16 + lq * 4 + q;
      if (row < nvalid) {
        float s = red[1][0][row] + red[1][1][row] + red[1][2][row] + red[1][3][row];
        float sc = gatearr[row] / s;
        int orow = rowarr[row] & 0xFFFF;
        float* yr = y + (size_t)orow * 512;
        #pragma unroll
        for (int n0 = 0; n0 < 8; n0++) {
          int colo = (w * 8 + n0) * 16 + lr;
          atomicAdd(yr + colo, acc2[m0][n0][q] * sc);
        }
      }
    }
  }
}

// ---------------- launch ----------------
extern "C" void kernel_launch(void* const* d_in, const int* in_sizes, int n_in,
                              void* d_out, int out_size, void* d_ws, size_t ws_size,
                              hipStream_t stream) {
  (void)in_sizes; (void)n_in; (void)out_size; (void)ws_size;
  const float* x  = (const float*)d_in[0];
  const float* wg = (const float*)d_in[1];
  const float* w1 = (const float*)d_in[2];
  const float* b1 = (const float*)d_in[3];
  const float* w2 = (const float*)d_in[4];
  const float* b2 = (const float*)d_in[5];
  float* y = (float*)d_out;

  char* ws = (char*)d_ws;
  size_t off = 0;
  auto alloc = [&](size_t bytes) -> char* {
    char* p = ws + off;
    off += (bytes + 255) & ~(size_t)255;
    return p;
  };
  f16*   w1fr       = (f16*)  alloc((size_t)16 * 512 * 1024 * 2);
  f16*   w2fr       = (f16*)  alloc((size_t)16 * 1024 * 512 * 2);
  int*   tk_idx     = (int*)  alloc((size_t)16384 * 4 * 4);
  float* tk_gate    = (float*)alloc((size_t)16384 * 4 * 4);
  int*   rows_pk    = (int*)  alloc((size_t)16 * 16384 * 4);
  float* gates_l    = (float*)alloc((size_t)16 * 16384 * 4);
  int*   partial    = (int*)  alloc(16 * 64 * 4);
  int*   chunk_base = (int*)  alloc(16 * 64 * 4);
  int*   count      = (int*)  alloc(256);
  // total ~34.6 MB

  k_cvt_w1<<<dim3(4096), dim3(256), 0, stream>>>(w1, w1fr);
  k_cvt_w2<<<dim3(4096), dim3(256), 0, stream>>>(w2, w2fr);
  k_gate<<<dim3(4096), dim3(256), 0, stream>>>(x, wg, tk_idx, tk_gate);
  k_route_count<<<dim3(1024), dim3(256), 0, stream>>>(tk_idx, partial);
  k_route_scan<<<dim3(1), dim3(64), 0, stream>>>(partial, chunk_base, count);
  k_route_scatter<<<dim3(1024), dim3(256), 0, stream>>>(tk_idx, tk_gate, chunk_base,
                                                        rows_pk, gates_l);
  k_zero<<<dim3(8192), dim3(256), 0, stream>>>((float4*)y);
  k_expert<<<dim3(16 * 512), dim3(256), 0, stream>>>(x, w1fr, w2fr, b1, b2,
                                                     count, rows_pk, gates_l, y);
}